// Round 18
// baseline (1202.708 us; speedup 1.0000x reference)
//
#include <hip/hip_runtime.h>

typedef unsigned short u16;
typedef unsigned int u32;
typedef __attribute__((ext_vector_type(8))) short bfrag;   // 8 x bf16
typedef __attribute__((ext_vector_type(4))) float f32x4;

#define SROW 1032   // padded LDS row stride (bf16 elems): 2064 B
#define ACCW 68     // sh_acc row stride in f32 (64 cols + 4 pad, quad-aligned)

__device__ __forceinline__ u16 f2bf(float x) {
    unsigned int v = __float_as_uint(x);
    return (u16)((v + 0x7FFFu + ((v >> 16) & 1u)) >> 16);   // RNE
}

// tanh(x) = 1 - 2/(e^{2x}+1): inf-safe.
__device__ __forceinline__ float fast_tanh(float x) {
    float e = __builtin_amdgcn_exp2f(x * 2.885390081777927f);
    return __builtin_fmaf(-2.0f, __builtin_amdgcn_rcpf(e + 1.0f), 1.0f);
}

// ---------------- prologue: bf16 conversions + 64x64 diag-block transpose (f32) ----------------
// diagT[bb][i][j] = Bs[64bb+j, 64bb+i] for j>i else 0  (weight from unit i to unit j)
__global__ void ren_prologue(const float* __restrict__ Bs, const float* __restrict__ Bw,
                             const float* __restrict__ Ds, const float* __restrict__ Dw,
                             u16* __restrict__ bs16, u16* __restrict__ bw16,
                             u16* __restrict__ ds16, u16* __restrict__ dw16,
                             float* __restrict__ diagT)
{
    const int g = blockIdx.x * 256 + threadIdx.x;
    if (g < 262144) {
        const int idx = g * 4;
        const int i = idx >> 10, j = idx & 1023;
        const float4 v = *reinterpret_cast<const float4*>(Bs + idx);
        u16 o[4];
        o[0] = (j + 0 < i) ? f2bf(v.x) : (u16)0;
        o[1] = (j + 1 < i) ? f2bf(v.y) : (u16)0;
        o[2] = (j + 2 < i) ? f2bf(v.z) : (u16)0;
        o[3] = (j + 3 < i) ? f2bf(v.w) : (u16)0;
        *reinterpret_cast<uint2*>(bs16 + idx) = *reinterpret_cast<const uint2*>(o);
    } else if (g < 294912) {
        const int idx = (g - 262144) * 4;
        const float4 v = *reinterpret_cast<const float4*>(Bw + idx);
        u16 o[4] = { f2bf(v.x), f2bf(v.y), f2bf(v.z), f2bf(v.w) };
        *reinterpret_cast<uint2*>(bw16 + idx) = *reinterpret_cast<const uint2*>(o);
    } else if (g < 327680) {
        const int idx = (g - 294912) * 4;
        const float4 v = *reinterpret_cast<const float4*>(Ds + idx);
        u16 o[4] = { f2bf(v.x), f2bf(v.y), f2bf(v.z), f2bf(v.w) };
        *reinterpret_cast<uint2*>(ds16 + idx) = *reinterpret_cast<const uint2*>(o);
    } else if (g < 331776) {
        const int idx = (g - 327680) * 4;
        const float4 v = *reinterpret_cast<const float4*>(Dw + idx);
        u16 o[4] = { f2bf(v.x), f2bf(v.y), f2bf(v.z), f2bf(v.w) };
        *reinterpret_cast<uint2*>(dw16 + idx) = *reinterpret_cast<const uint2*>(o);
    } else if (g < 348160) {
        const int lin0 = (g - 331776) * 4;
        #pragma unroll
        for (int t = 0; t < 4; ++t) {
            const int idx = lin0 + t;
            const int bb = idx >> 12, rem = idx & 4095, i = rem >> 6, j = rem & 63;
            diagT[idx] = (j > i) ? Bs[(size_t)(bb * 64 + j) * 1024 + (bb * 64 + i)] : 0.0f;
        }
    }
}

// ---------------- main: producer/consumer, BLK=64 (16 handoffs), 2 wgs/CU ----------------
// 512 wgs x 192 threads, 16 batch rows/wg. Waves 0,1: GEMM producers (each owns
// 2 col-tiles of the 64-unit target block). Wave 2: serial consumer (lanes 0-15
// = batch rows), hierarchical 8-wide sub-blocks over a 64-step block, weights
// from LDS sh_dT (dbuf 2x16KB).
__global__ __launch_bounds__(192, 2) void ren_main(
    const float* __restrict__ u,
    const u16* __restrict__ bs16, const u16* __restrict__ bw16,
    const u16* __restrict__ ds16, const u16* __restrict__ dw16,
    const float* __restrict__ diagT,
    float* __restrict__ out)
{
    __shared__ __align__(16) u16   sh_S[16 * SROW];    // s history bf16 [16][1024+pad]
    __shared__ __align__(16) float sh_acc[16 * ACCW];  // pre-activation tile [16][68]
    __shared__ __align__(16) float sh_dT[2][4096];     // dbuf diag block f32 [64][64]

    const int tid  = threadIdx.x;
    const int wave = tid >> 6;
    const int lane = tid & 63;
    const int lr   = lane & 15;
    const int lk8  = (lane >> 4) << 3;
    const int row0 = blockIdx.x << 4;      // 16 batch rows per wg

    bfrag fu[4];                           // u A-frags (GEMM waves only)
    f32x4 acc[2];                          // 2 col-tiles per GEMM wave

    if (wave < 2) {
        const float* up = u + (size_t)(row0 + lr) * 128 + lk8;
        #pragma unroll
        for (int kk = 0; kk < 4; ++kk) {
            float4 a = *reinterpret_cast<const float4*>(up + kk * 32);
            float4 c = *reinterpret_cast<const float4*>(up + kk * 32 + 4);
            bfrag f;
            f[0] = (short)f2bf(a.x); f[1] = (short)f2bf(a.y);
            f[2] = (short)f2bf(a.z); f[3] = (short)f2bf(a.w);
            f[4] = (short)f2bf(c.x); f[5] = (short)f2bf(c.y);
            f[6] = (short)f2bf(c.z); f[7] = (short)f2bf(c.w);
            fu[kk] = f;
        }
        // stage dT block 0 (4096 f32 by threads 0-127, interleaved for banks)
        {
            const float4* g4 = reinterpret_cast<const float4*>(diagT);
            float4* dd = reinterpret_cast<float4*>(&sh_dT[0][0]);
            #pragma unroll
            for (int k = 0; k < 8; ++k) dd[k * 128 + tid] = g4[k * 128 + tid];
        }
        // block 0 pre-activations = Bu only (units 0..63, two 16-col tiles/wave)
        #pragma unroll
        for (int a = 0; a < 2; ++a) {
            acc[a] = (f32x4){0.f, 0.f, 0.f, 0.f};
            const int ng = ((wave << 1) + a) * 16 + lr;
            const u16* p0 = bw16 + (size_t)ng * 128 + lk8;
            #pragma unroll
            for (int kk = 0; kk < 4; ++kk)
                acc[a] = __builtin_amdgcn_mfma_f32_16x16x32_bf16(fu[kk], *reinterpret_cast<const bfrag*>(p0 + kk * 32), acc[a], 0, 0, 0);
            const int m = (lane >> 4) << 2;
            #pragma unroll
            for (int rr = 0; rr < 4; ++rr)
                sh_acc[(m + rr) * ACCW + ((wave << 1) + a) * 16 + lr] = acc[a][rr];
        }
    }
    __syncthreads();

    for (int b = 0; b < 16; ++b) {
        bfrag bfin[2][2];                  // finish B-frags (2 tiles x 2 k-chunks)
        const int nb = b + 1;

        if (wave == 2) {
            // ---------- serial consumer: hierarchical solve of 64-step block b ----------
            if (lane < 16) {
                float part[64];
                const float* accr = sh_acc + lane * ACCW;
                #pragma unroll
                for (int q = 0; q < 16; ++q) {
                    float4 v = reinterpret_cast<const float4*>(accr)[q];
                    part[4*q+0] = v.x; part[4*q+1] = v.y; part[4*q+2] = v.z; part[4*q+3] = v.w;
                }
                const float4* dT4 = reinterpret_cast<const float4*>(&sh_dT[b & 1][0]);  // [64][16 quads]
                u16* srow = sh_S + lane * SROW + (b << 6);

                #pragma unroll
                for (int g = 0; g < 8; ++g) {
                    // (a) diagonal 8x8: preload 16 quads as one independent group
                    float4 dq0[8], dq1[8];
                    #pragma unroll
                    for (int i = 0; i < 8; ++i) {
                        dq0[i] = dT4[(8 * g + i) * 16 + 2 * g];
                        dq1[i] = dT4[(8 * g + i) * 16 + 2 * g + 1];
                    }
                    float s8[8];
                    #pragma unroll
                    for (int i = 0; i < 8; ++i) {
                        float s = fast_tanh(part[8 * g + i]);
                        s8[i] = s;
                        part[8*g+0] = __builtin_fmaf(dq0[i].x, s, part[8*g+0]);
                        part[8*g+1] = __builtin_fmaf(dq0[i].y, s, part[8*g+1]);
                        part[8*g+2] = __builtin_fmaf(dq0[i].z, s, part[8*g+2]);
                        part[8*g+3] = __builtin_fmaf(dq0[i].w, s, part[8*g+3]);
                        part[8*g+4] = __builtin_fmaf(dq1[i].x, s, part[8*g+4]);
                        part[8*g+5] = __builtin_fmaf(dq1[i].y, s, part[8*g+5]);
                        part[8*g+6] = __builtin_fmaf(dq1[i].z, s, part[8*g+6]);
                        part[8*g+7] = __builtin_fmaf(dq1[i].w, s, part[8*g+7]);
                    }
                    {   // pack the 8 fresh s values -> sh_S (one 16B store)
                        uint4 pk;
                        u32 r0 = (__float_as_uint(s8[0]) + 0x8000u) >> 16;
                        u32 r1 = (__float_as_uint(s8[1]) + 0x8000u) >> 16;
                        u32 r2 = (__float_as_uint(s8[2]) + 0x8000u) >> 16;
                        u32 r3 = (__float_as_uint(s8[3]) + 0x8000u) >> 16;
                        u32 r4 = (__float_as_uint(s8[4]) + 0x8000u) >> 16;
                        u32 r5 = (__float_as_uint(s8[5]) + 0x8000u) >> 16;
                        u32 r6 = (__float_as_uint(s8[6]) + 0x8000u) >> 16;
                        u32 r7 = (__float_as_uint(s8[7]) + 0x8000u) >> 16;
                        pk.x = r0 | (r1 << 16);
                        pk.y = r2 | (r3 << 16);
                        pk.z = r4 | (r5 << 16);
                        pk.w = r6 | (r7 << 16);
                        *reinterpret_cast<uint4*>(srow + 8 * g) = pk;
                    }
                    // (b) panel: units 8(g+1)..63 += W * s8 — off-chain, 2-row chunks,
                    //     quad span split into passes of <=7 to bound live registers
                    #pragma unroll
                    for (int h = 0; h < 4; ++h) {
                        #pragma unroll
                        for (int qs = 2 * g + 2; qs < 16; qs += 7) {
                            const int qe = (qs + 7 < 16) ? qs + 7 : 16;
                            float4 pw[2][7];
                            #pragma unroll
                            for (int r = 0; r < 2; ++r)
                                #pragma unroll
                                for (int q = qs; q < qe; ++q)
                                    pw[r][q - qs] = dT4[(8 * g + 2 * h + r) * 16 + q];
                            #pragma unroll
                            for (int r = 0; r < 2; ++r) {
                                float s = s8[2 * h + r];
                                #pragma unroll
                                for (int q = qs; q < qe; ++q) {
                                    float4 w = pw[r][q - qs];
                                    part[4*q+0] = __builtin_fmaf(w.x, s, part[4*q+0]);
                                    part[4*q+1] = __builtin_fmaf(w.y, s, part[4*q+1]);
                                    part[4*q+2] = __builtin_fmaf(w.z, s, part[4*q+2]);
                                    part[4*q+3] = __builtin_fmaf(w.w, s, part[4*q+3]);
                                }
                            }
                        }
                    }
                }
            }
        } else if (b < 15) {
            // ---------- GEMM producers: partial for block b+1 (k chunks < 2b) ----------
            float4 st[8];
            {   // stage dT[b+1] loads early (landed after the GEMM)
                const float4* g4 = reinterpret_cast<const float4*>(diagT + (nb << 12));
                #pragma unroll
                for (int k = 0; k < 8; ++k) st[k] = g4[k * 128 + tid];
            }
            #pragma unroll
            for (int a = 0; a < 2; ++a) {
                const int ng = (nb << 6) + ((wave << 1) + a) * 16 + lr;
                const u16* bsp = bs16 + (size_t)ng * 1024 + lk8;
                bfin[a][0] = *reinterpret_cast<const bfrag*>(bsp + (b << 6));
                bfin[a][1] = *reinterpret_cast<const bfrag*>(bsp + (b << 6) + 32);

                acc[a] = (f32x4){0.f, 0.f, 0.f, 0.f};
                const u16* p0 = bw16 + (size_t)ng * 128 + lk8;
                #pragma unroll
                for (int kk = 0; kk < 4; ++kk)
                    acc[a] = __builtin_amdgcn_mfma_f32_16x16x32_bf16(fu[kk], *reinterpret_cast<const bfrag*>(p0 + kk * 32), acc[a], 0, 0, 0);

                const u16* ssp = sh_S + lr * SROW + lk8;
                const int nkc = b << 1;
                #pragma unroll 8
                for (int kc = 0; kc < nkc; ++kc) {
                    bfrag af = *reinterpret_cast<const bfrag*>(ssp + (kc << 5));
                    acc[a] = __builtin_amdgcn_mfma_f32_16x16x32_bf16(af, *reinterpret_cast<const bfrag*>(bsp + (kc << 5)), acc[a], 0, 0, 0);
                }
            }
            {   // land staged dT[b+1]
                float4* dd = reinterpret_cast<float4*>(&sh_dT[nb & 1][0]);
                #pragma unroll
                for (int k = 0; k < 8; ++k) dd[k * 128 + tid] = st[k];
            }
        }
        __syncthreads();   // s_b visible; partials done

        if (wave < 2 && b < 15) {
            // ---------- finish block b+1 with the two fresh s_b k-slices ----------
            const u16* ssp = sh_S + lr * SROW + lk8;
            bfrag af0 = *reinterpret_cast<const bfrag*>(ssp + (b << 6));
            bfrag af1 = *reinterpret_cast<const bfrag*>(ssp + (b << 6) + 32);
            #pragma unroll
            for (int a = 0; a < 2; ++a) {
                acc[a] = __builtin_amdgcn_mfma_f32_16x16x32_bf16(af0, bfin[a][0], acc[a], 0, 0, 0);
                acc[a] = __builtin_amdgcn_mfma_f32_16x16x32_bf16(af1, bfin[a][1], acc[a], 0, 0, 0);
                const int m = (lane >> 4) << 2;
                #pragma unroll
                for (int rr = 0; rr < 4; ++rr)
                    sh_acc[(m + rr) * ACCW + ((wave << 1) + a) * 16 + lr] = acc[a][rr];
            }
        }
        __syncthreads();   // sh_acc ready for serial(b+1)
    }

    if (wave >= 2) return;

    // ---------------- epilogue: y = s @ Ds^T + u @ D^T  (16 x 128 per wg) ----------------
    const int nt = wave & 1;
    f32x4 ey[4];
    #pragma unroll
    for (int t = 0; t < 4; ++t) ey[t] = (f32x4){0.f, 0.f, 0.f, 0.f};

    const u16* ssp = sh_S + lr * SROW + lk8;
    #pragma unroll 4
    for (int kc = 0; kc < 32; ++kc) {
        bfrag af = *reinterpret_cast<const bfrag*>(ssp + (kc << 5));
        #pragma unroll
        for (int t = 0; t < 4; ++t) {
            const int n = ((nt << 2) + t) * 16 + lr;
            bfrag bf = *reinterpret_cast<const bfrag*>(ds16 + (size_t)n * 1024 + (kc << 5) + lk8);
            ey[t] = __builtin_amdgcn_mfma_f32_16x16x32_bf16(af, bf, ey[t], 0, 0, 0);
        }
    }
    #pragma unroll
    for (int kk = 0; kk < 4; ++kk) {
        #pragma unroll
        for (int t = 0; t < 4; ++t) {
            const int n = ((nt << 2) + t) * 16 + lr;
            bfrag bf = *reinterpret_cast<const bfrag*>(dw16 + n * 128 + (kk << 5) + lk8);
            ey[t] = __builtin_amdgcn_mfma_f32_16x16x32_bf16(fu[kk], bf, ey[t], 0, 0, 0);
        }
    }
    {
        const int mbase = row0 + ((lane >> 4) << 2);
        #pragma unroll
        for (int t = 0; t < 4; ++t) {
            const int n = ((nt << 2) + t) * 16 + lr;
            #pragma unroll
            for (int rr = 0; rr < 4; ++rr)
                out[(size_t)(mbase + rr) * 128 + n] = ey[t][rr];
        }
    }
}

extern "C" void kernel_launch(void* const* d_in, const int* in_sizes, int n_in,
                              void* d_out, int out_size, void* d_ws, size_t ws_size,
                              hipStream_t stream)
{
    const float* u  = (const float*)d_in[0];   // [8192,128]
    const float* Bw = (const float*)d_in[1];   // [1024,128]
    const float* Bs = (const float*)d_in[2];   // [1024,1024]
    const float* Ds = (const float*)d_in[3];   // [128,1024]
    const float* Dw = (const float*)d_in[4];   // [128,128]
    float* out = (float*)d_out;

    u16* bs16 = (u16*)d_ws;                    // 1024*1024 bf16
    u16* bw16 = bs16 + 1024 * 1024;            // 1024*128
    u16* ds16 = bw16 + 1024 * 128;             // 128*1024
    u16* dw16 = ds16 + 128 * 1024;             // 128*128
    float* diagT = (float*)(dw16 + 128 * 128); // 16 blocks x 64x64 f32, transposed

    ren_prologue<<<1360, 256, 0, stream>>>(Bs, Bw, Ds, Dw, bs16, bw16, ds16, dw16, diagT);
    ren_main<<<512, 192, 0, stream>>>(u, bs16, bw16, ds16, dw16, diagT, out);
}